// Round 13
// baseline (129.631 us; speedup 1.0000x reference)
//
#include <hip/hip_runtime.h>
#include <hip/hip_bf16.h>

#define NBLK 8
#define DIN 512
#define DOUT 512
#define NFEAT 4096      // NBLK * DIN
#define BATCH 8192
#define NT 16           // DIN / 32 K-steps
#define BM 128
#define BN 128          // per-block N panel (persistent in LDS)
#define MT_PER_BLK 8    // mt tiles per block (64 / 8 groups)

typedef __attribute__((ext_vector_type(8))) short short8;
typedef __attribute__((ext_vector_type(4))) float f32x4;

static __device__ __forceinline__ short f2bf16(float f) {
  __bf16 h = (__bf16)f;               // RNE; compiler packs into v_cvt_pk_bf16_f32
  return __builtin_bit_cast(short, h);
}

static __device__ __forceinline__ short8 cvt8(f32x4 lo, f32x4 hi) {
  short8 o;
  o[0] = f2bf16(lo[0]); o[1] = f2bf16(lo[1]); o[2] = f2bf16(lo[2]); o[3] = f2bf16(lo[3]);
  o[4] = f2bf16(hi[0]); o[5] = f2bf16(hi[1]); o[6] = f2bf16(hi[2]); o[7] = f2bf16(hi[3]);
  return o;
}

static __device__ __forceinline__ void gload_lds16(const void* g, void* l) {
  __builtin_amdgcn_global_load_lds(
      (const __attribute__((address_space(1))) void*)g,
      (__attribute__((address_space(3))) void*)l, 16, 0, 0);
}

// R13: persistent-B. Single kernel, no pre-pass, no workspace.
// Grid 256 (1 block/CU). Block (nb = b&7 = XCD id, nt = (b>>3)&3, grp = b>>5)
// owns a 128-col B panel: converts W fp32 -> bf16 fragment-major into a
// 128 KB LDS residency ONCE, then runs 8 mt-tiles (128x128 each).
// K-loop stages A ONLY (16 KB/step, 16x 1KB DMA) into a 2-buf 32 KB region:
// R11's proven schedule (vmcnt(0) -> barrier -> stage(t+1) -> compute(t)).
// B fragment reads are linear/conflict-free, indexed by t, never staged.
// Next tile's A(0) prefetch + y-store drain hide under the epilogue.
// LDS: 128 KB (B) + 32 KB (A) = 163840 B exactly.
__global__ __launch_bounds__(512, 1) void blocklinear_kernel(
    const float* __restrict__ x, const float* __restrict__ W,
    const float* __restrict__ bias, float* __restrict__ y)
{
  const int b   = blockIdx.x;
  const int nb  = b & 7;         // == XCD id (HW round-robin b%8)
  const int nt  = (b >> 3) & 3;  // N quarter (cols nt*128..+128 of DOUT)
  const int grp = b >> 5;        // mt group: tiles grp*8 .. grp*8+7

  const int tid  = threadIdx.x;
  const int lane = tid & 63;
  const int w    = tid >> 6;     // wave 0..7
  const int wr   = w >> 2;       // M-row 0..1 (rows wr*64..+64)
  const int wn   = w & 3;        // N 32-col strip 0..3
  const int l15  = lane & 15;
  const int k16  = lane >> 4;

  __shared__ __align__(16) float Abuf[2][BM * 32];   // 32 KB (A dbuf)
  __shared__ __align__(16) short Bp[BN * DIN];       // 128 KB (persistent B)

  // ---- B prologue: wave w converts col-frag cb=w (16 cols), all 16 t.
  // Layout: Bp[(cb*16 + t)*512 + lane*8 + j] = bf16(W[nb][cb*16+(lane&15)]
  //                                                 [t*32 + (lane>>4)*8 + j])
  {
    const float* wsrc = W + ((size_t)nb * DOUT + nt * BN + w * 16 + l15) * DIN + k16 * 8;
    short* bdst = Bp + (w * 16) * 512 + lane * 8;
#pragma unroll
    for (int t = 0; t < 16; ++t) {
      f32x4 lo = *(const f32x4*)(wsrc + t * 32);
      f32x4 hi = *(const f32x4*)(wsrc + t * 32 + 4);
      *(short8*)(bdst + t * 512) = cvt8(lo, hi);
    }
  }
  __syncthreads();

  // ---- A staging geometry: 16 x 1KB DMAs per step (128 rows x 128 B);
  // wave w does 2 (i=0,1), rows w*16 + i*8 + (l>>3). Dest chunk l&7 linear;
  // source chunk pre-XOR'd (l&7)^(l>>3): slot s of row r = data chunk s^(r&7).
  const int l8 = lane >> 3;
  const int c  = lane & 7;
  const float* asrc[2];
#pragma unroll
  for (int i = 0; i < 2; ++i) {
    const int gr = grp * (MT_PER_BLK * BM) + w * 16 + i * 8 + l8;  // tile 0 row
    asrc[i] = x + (size_t)gr * NFEAT + nb * DIN + ((c ^ l8) << 2);
  }

#define STAGE_A(IT, T, BUF)                                                 \
  {                                                                         \
    _Pragma("unroll")                                                       \
    for (int i = 0; i < 2; ++i)                                             \
      gload_lds16(asrc[i] + (size_t)(IT) * (BM * NFEAT) + (T) * 32,         \
                  &Abuf[BUF][(w * 16 + i * 8) * 32]);                       \
  }

  // ---- A fragment read offsets: row = wr*64 + m*16 + l15 (row&7 == l15&7);
  // addr = row*32 + slot*4, slot = (2k16 / 2k16+1) ^ (l15&7).
  const int ra_base = (wr * 64 + l15) * 32;
  const int ra_lo   = ra_base + (((2 * k16)     ^ (l15 & 7)) << 2);
  const int ra_hi   = ra_base + (((2 * k16 + 1) ^ (l15 & 7)) << 2);

  f32x4 acc[4][2];

#define COMPUTE(BUF, T)                                                     \
  {                                                                         \
    const float* la = &Abuf[BUF][0];                                        \
    short8 af[4], bf[2];                                                    \
    _Pragma("unroll")                                                       \
    for (int m = 0; m < 4; ++m) {                                           \
      f32x4 lo = *(const f32x4*)(la + m * 512 + ra_lo);                     \
      f32x4 hi = *(const f32x4*)(la + m * 512 + ra_hi);                     \
      af[m] = cvt8(lo, hi);                                                 \
    }                                                                       \
    _Pragma("unroll")                                                       \
    for (int n = 0; n < 2; ++n)                                             \
      bf[n] = *(const short8*)(Bp + ((wn * 2 + n) * 16 + (T)) * 512 + lane * 8); \
    __builtin_amdgcn_s_setprio(1);                                          \
    _Pragma("unroll")                                                       \
    for (int m = 0; m < 4; ++m)                                             \
      _Pragma("unroll")                                                     \
      for (int n = 0; n < 2; ++n)                                           \
        acc[m][n] = __builtin_amdgcn_mfma_f32_16x16x32_bf16(af[m], bf[n], acc[m][n], 0, 0, 0); \
    __builtin_amdgcn_s_setprio(0);                                          \
  }

  // Step: drain stage(t) (and, at tile start, last tile's y-stores — both
  // issued before the epilogue/compute that covered them); barrier;
  // stage(t+1) — or next tile's step 0 at t=15 (hides under epilogue);
  // compute(t).
#define STEPX(IT, T)                                                        \
  {                                                                         \
    __builtin_amdgcn_sched_barrier(0);                                      \
    asm volatile("s_waitcnt vmcnt(0)" ::: "memory");                        \
    __builtin_amdgcn_s_barrier();                                           \
    __builtin_amdgcn_sched_barrier(0);                                      \
    if ((T) < 15) { STAGE_A((IT), (T) + 1, ((T) + 1) & 1); }                \
    else if ((IT) + 1 < MT_PER_BLK) { STAGE_A((IT) + 1, 0, 0); }            \
    COMPUTE((T) & 1, (T));                                                  \
  }

  STAGE_A(0, 0, 0);

#pragma unroll 1
  for (int it = 0; it < MT_PER_BLK; ++it) {
#pragma unroll
    for (int m = 0; m < 4; ++m)
#pragma unroll
      for (int n = 0; n < 2; ++n)
        acc[m][n] = (f32x4){0.f, 0.f, 0.f, 0.f};

    STEPX(it, 0)  STEPX(it, 1)  STEPX(it, 2)  STEPX(it, 3)
    STEPX(it, 4)  STEPX(it, 5)  STEPX(it, 6)  STEPX(it, 7)
    STEPX(it, 8)  STEPX(it, 9)  STEPX(it, 10) STEPX(it, 11)
    STEPX(it, 12) STEPX(it, 13) STEPX(it, 14) STEPX(it, 15)

    // epilogue: C/D layout col = lane&15, row = (lane>>4)*4 + j [m89-verified]
    const int mt   = grp * MT_PER_BLK + it;
    const int col0 = nt * BN + wn * 32;
    const int row0 = mt * BM + wr * 64;
    const float* bptr = bias + nb * DOUT + col0;
#pragma unroll
    for (int n = 0; n < 2; ++n) {
      const float bv = bptr[n * 16 + l15];
      const size_t col = (size_t)nb * DOUT + col0 + n * 16 + l15;
#pragma unroll
      for (int m = 0; m < 4; ++m) {
        const int row = row0 + m * 16 + k16 * 4;
        float* yp = y + (size_t)row * NFEAT + col;
#pragma unroll
        for (int j = 0; j < 4; ++j)
          yp[(size_t)j * NFEAT] = acc[m][n][j] + bv;
      }
    }
  }
}

extern "C" void kernel_launch(void* const* d_in, const int* in_sizes, int n_in,
                              void* d_out, int out_size, void* d_ws, size_t ws_size,
                              hipStream_t stream) {
  const float* x  = (const float*)d_in[0];
  const float* W  = (const float*)d_in[1];
  const float* bi = (const float*)d_in[2];
  float* y = (float*)d_out;
  const int grid = NBLK * (DOUT / BN) * (BATCH / (BM * MT_PER_BLK));  // 256
  blocklinear_kernel<<<grid, 512, 0, stream>>>(x, W, bi, y);
}

// Round 14
// 103.721 us; speedup vs baseline: 1.2498x; 1.2498x over previous
//
#include <hip/hip_runtime.h>
#include <hip/hip_bf16.h>

#define NBLK 8
#define DIN 512
#define DOUT 512
#define NFEAT 4096      // NBLK * DIN
#define BATCH 8192
#define NT 16           // DIN / 32 K-steps
#define BM 128
#define BN 128

typedef __attribute__((ext_vector_type(8))) short short8;
typedef __attribute__((ext_vector_type(4))) float f32x4;

static __device__ __forceinline__ short f2bf16(float f) {
  __bf16 h = (__bf16)f;               // RNE; compiler packs into v_cvt_pk_bf16_f32
  return __builtin_bit_cast(short, h);
}

static __device__ __forceinline__ short8 cvt8(f32x4 lo, f32x4 hi) {
  short8 o;
  o[0] = f2bf16(lo[0]); o[1] = f2bf16(lo[1]); o[2] = f2bf16(lo[2]); o[3] = f2bf16(lo[3]);
  o[4] = f2bf16(hi[0]); o[5] = f2bf16(hi[1]); o[6] = f2bf16(hi[2]); o[7] = f2bf16(hi[3]);
  return o;
}

static __device__ __forceinline__ void gload_lds16(const void* g, void* l) {
  __builtin_amdgcn_global_load_lds(
      (const __attribute__((address_space(1))) void*)g,
      (__attribute__((address_space(3))) void*)l, 16, 0, 0);
}

// Pre-pass: W [8][512][512] fp32 -> Wp fragment-major bf16 (~3-4 us total).
// Chunk (nb,cb,t) is 1 KB contiguous: lane l holds col cb*16+(l&15),
// k = t*32+(l>>4)*8.
__global__ __launch_bounds__(256) void wprep_kernel(const float* __restrict__ W,
                                                    short* __restrict__ Wp) {
  const int gid  = blockIdx.x * 256 + threadIdx.x;
  const int lane = gid & 63;
  const int t    = (gid >> 6) & 15;
  const int cb   = (gid >> 10) & 31;
  const int nb   = gid >> 15;
  const int col  = cb * 16 + (lane & 15);
  const int k    = t * 32 + (lane >> 4) * 8;
  const float* src = W + (size_t)(nb * DOUT + col) * DIN + k;
  f32x4 lo = *(const f32x4*)src;
  f32x4 hi = *(const f32x4*)(src + 4);
  *(short8*)(Wp + (size_t)gid * 8) = cvt8(lo, hi);
}

// R14: the untested matrix cell — counted distance-2 pipeline (R7's proven
// schedule) WITH 2-block/CU co-residency (R11's TLP). 128x128 tile,
// 256 threads, 4 waves (2x2), wave tile 64x64 (acc=64 VGPR).
// A (x fp32) 3-buf 48 KB + B (Wp bf16) 3-buf 24 KB = 72 KB -> 2 blocks/CU.
// Per step: 16 A-DMAs + 8 B-DMAs (6 per wave -> vmcnt(6) = one stage-group
// in flight); stage(t+2) after barrier(t) (race-free: buf (t+2)%3 was last
// read at t-1, and those reads completed before each wave's barrier).
template <bool WPREP>
__global__ __launch_bounds__(256, 4) void blocklinear_kernel(
    const float* __restrict__ x, const float* __restrict__ W,
    const short* __restrict__ Wp, const float* __restrict__ bias,
    float* __restrict__ y)
{
  // XCD swizzle (bijective: 2048 % 8 == 0): one nb per XCD, nt innermost
  // (4 nt-siblings share an x M-panel on one XCD's L2/L3 path).
  const int b       = blockIdx.x;
  const int logical = (b & 7) * 256 + (b >> 3);
  const int nb  = logical >> 8;
  const int rem = logical & 255;
  const int mt  = rem >> 2;    // 0..63
  const int nt  = rem & 3;     // 0..3

  const int tid  = threadIdx.x;
  const int lane = tid & 63;
  const int w    = tid >> 6;   // wave 0..3
  const int wr   = w >> 1;     // M-row 0..1 (rows wr*64..+64)
  const int wc   = w & 1;      // N-col 0..1 (cols wc*64..+64)
  const int l15  = lane & 15;
  const int k16  = lane >> 4;

  __shared__ __align__(16) float Abuf[3][BM * 32];   // 3 x 16 KB
  __shared__ __align__(16) short Bbuf[3][BN * 32];   // 3 x  8 KB  (72 KB)

  // --- A staging: 16 x 1KB DMAs (128 rows x 128 B); wave w does 4 (i=0..3),
  // rows w*32+i*8+(l>>3). Dest chunk l&7 (linear); source chunk pre-XOR'd
  // (l&7)^(l>>3): stored slot s of row r holds data chunk s^(r&7).
  const int l8 = lane >> 3;
  const int c  = lane & 7;
  const float* asrc[4];
#pragma unroll
  for (int i = 0; i < 4; ++i) {
    const int gr = mt * BM + w * 32 + i * 8 + l8;
    asrc[i] = x + (size_t)gr * NFEAT + nb * DIN + ((c ^ l8) << 2);
  }
  // --- B staging: 8 x 1KB chunks (one per 16-col frag); wave w does 2.
  const short* bsrc[2];
#pragma unroll
  for (int i = 0; i < 2; ++i) {
    const int cb = nt * 8 + w * 2 + i;
    bsrc[i] = WPREP ? Wp + ((size_t)(nb * 32 + cb) * 16) * 512 + lane * 8 : nullptr;
  }

#define STAGE(buf, t)                                                       \
  {                                                                         \
    _Pragma("unroll")                                                       \
    for (int i = 0; i < 4; ++i)                                             \
      gload_lds16(asrc[i] + (t) * 32, &Abuf[buf][(w * 32 + i * 8) * 32]);   \
    if constexpr (WPREP) {                                                  \
      _Pragma("unroll")                                                     \
      for (int i = 0; i < 2; ++i)                                           \
        gload_lds16(bsrc[i] + (t) * 512, &Bbuf[buf][(w * 2 + i) * 512]);    \
    }                                                                       \
  }

  // --- A fragment read offsets (floats): row = wr*64 + m*16 + l15
  // (row&7 == l15&7); addr = row*32 + slot*4, slot = (2k16 / 2k16+1)^(l15&7).
  const int ra_base = (wr * 64 + l15) * 32;
  const int ra_lo   = ra_base + (((2 * k16)     ^ (l15 & 7)) << 2);
  const int ra_hi   = ra_base + (((2 * k16 + 1) ^ (l15 & 7)) << 2);

  f32x4 acc[4][4];
#pragma unroll
  for (int m = 0; m < 4; ++m)
#pragma unroll
    for (int n = 0; n < 4; ++n)
      acc[m][n] = (f32x4){0.f, 0.f, 0.f, 0.f};

#define COMPUTE(buf)                                                        \
  {                                                                         \
    const float* la = &Abuf[buf][0];                                        \
    const short* lb = &Bbuf[buf][0];                                        \
    short8 af[4], bf[4];                                                    \
    _Pragma("unroll")                                                       \
    for (int m = 0; m < 4; ++m) {                                           \
      f32x4 lo = *(const f32x4*)(la + m * 512 + ra_lo);                     \
      f32x4 hi = *(const f32x4*)(la + m * 512 + ra_hi);                     \
      af[m] = cvt8(lo, hi);                                                 \
    }                                                                       \
    if constexpr (WPREP) {                                                  \
      _Pragma("unroll")                                                     \
      for (int n = 0; n < 4; ++n)                                           \
        bf[n] = *(const short8*)(lb + (wc * 4 + n) * 512 + lane * 8);       \
    } else {                                                                \
      _Pragma("unroll")                                                     \
      for (int n = 0; n < 4; ++n) {                                         \
        const int col = nt * BN + wc * 64 + n * 16 + l15;                   \
        const float* bp = W + (size_t)nb * DOUT * DIN + (size_t)col * DIN + \
                          CUR_T * 32 + k16 * 8;                             \
        bf[n] = cvt8(*(const f32x4*)bp, *(const f32x4*)(bp + 4));           \
      }                                                                     \
    }                                                                       \
    __builtin_amdgcn_s_setprio(1);                                          \
    _Pragma("unroll")                                                       \
    for (int m = 0; m < 4; ++m)                                             \
      _Pragma("unroll")                                                     \
      for (int n = 0; n < 4; ++n)                                           \
        acc[m][n] = __builtin_amdgcn_mfma_f32_16x16x32_bf16(af[m], bf[n], acc[m][n], 0, 0, 0); \
    __builtin_amdgcn_s_setprio(0);                                          \
  }

  // Step t: wait t's stage (6/wave in flight after = t+1's group -> vmcnt(6));
  // barrier; stage(t+2); compute(t). The co-resident block covers the wait.
#define STEP(t, VMC)                                                        \
  {                                                                         \
    const int CUR_T = (t);                                                  \
    (void)CUR_T;                                                            \
    __builtin_amdgcn_sched_barrier(0);                                      \
    asm volatile("s_waitcnt vmcnt(" #VMC ")" ::: "memory");                 \
    __builtin_amdgcn_s_barrier();                                           \
    __builtin_amdgcn_sched_barrier(0);                                      \
    if ((t) + 2 < NT) STAGE(((t) + 2) % 3, (t) + 2);                        \
    COMPUTE((t) % 3);                                                       \
  }

  STAGE(0, 0);
  STAGE(1, 1);

  if constexpr (WPREP) {
    STEP(0, 6)  STEP(1, 6)  STEP(2, 6)  STEP(3, 6)
    STEP(4, 6)  STEP(5, 6)  STEP(6, 6)  STEP(7, 6)
    STEP(8, 6)  STEP(9, 6)  STEP(10, 6) STEP(11, 6)
    STEP(12, 6) STEP(13, 6) STEP(14, 6) STEP(15, 0)
  } else {
    STEP(0, 4)  STEP(1, 4)  STEP(2, 4)  STEP(3, 4)
    STEP(4, 4)  STEP(5, 4)  STEP(6, 4)  STEP(7, 4)
    STEP(8, 4)  STEP(9, 4)  STEP(10, 4) STEP(11, 4)
    STEP(12, 4) STEP(13, 4) STEP(14, 4) STEP(15, 0)
  }

  // epilogue: C/D layout col = lane&15, row = (lane>>4)*4 + j  [m89-verified]
  const int col0 = nt * BN + wc * 64;
  const int row0 = mt * BM + wr * 64;
  const float* bptr = bias + nb * DOUT + col0;
#pragma unroll
  for (int n = 0; n < 4; ++n) {
    const float bv = bptr[n * 16 + l15];
    const size_t col = (size_t)nb * DOUT + col0 + n * 16 + l15;
#pragma unroll
    for (int m = 0; m < 4; ++m) {
      const int row = row0 + m * 16 + k16 * 4;
      float* yp = y + (size_t)row * NFEAT + col;
#pragma unroll
      for (int j = 0; j < 4; ++j)
        yp[(size_t)j * NFEAT] = acc[m][n][j] + bv;
    }
  }
}

extern "C" void kernel_launch(void* const* d_in, const int* in_sizes, int n_in,
                              void* d_out, int out_size, void* d_ws, size_t ws_size,
                              hipStream_t stream) {
  const float* x  = (const float*)d_in[0];
  const float* W  = (const float*)d_in[1];
  const float* bi = (const float*)d_in[2];
  float* y = (float*)d_out;
  const size_t wp_bytes = (size_t)NBLK * DOUT * DIN * sizeof(short);  // 4 MiB
  const int grid = NBLK * (BATCH / BM) * (DOUT / BN);                 // 2048

  if (ws_size >= wp_bytes) {
    short* Wp = (short*)d_ws;
    wprep_kernel<<<(NBLK * DOUT * DIN / 8) / 256, 256, 0, stream>>>(W, Wp);
    blocklinear_kernel<true><<<grid, 256, 0, stream>>>(x, W, Wp, bi, y);
  } else {
    blocklinear_kernel<false><<<grid, 256, 0, stream>>>(x, W, nullptr, bi, y);
  }
}

// Round 15
// 88.728 us; speedup vs baseline: 1.4610x; 1.1690x over previous
//
#include <hip/hip_runtime.h>
#include <hip/hip_bf16.h>

#define NBLK 8
#define DIN 512
#define DOUT 512
#define NFEAT 4096      // NBLK * DIN
#define BATCH 8192
#define NT 16           // DIN / 32 K-steps
#define BM 256
#define BN 256

typedef __attribute__((ext_vector_type(8))) short short8;
typedef __attribute__((ext_vector_type(4))) float f32x4;

static __device__ __forceinline__ short f2bf16(float f) {
  __bf16 h = (__bf16)f;               // RNE; compiler packs into v_cvt_pk_bf16_f32
  return __builtin_bit_cast(short, h);
}

static __device__ __forceinline__ short8 cvt8(f32x4 lo, f32x4 hi) {
  short8 o;
  o[0] = f2bf16(lo[0]); o[1] = f2bf16(lo[1]); o[2] = f2bf16(lo[2]); o[3] = f2bf16(lo[3]);
  o[4] = f2bf16(hi[0]); o[5] = f2bf16(hi[1]); o[6] = f2bf16(hi[2]); o[7] = f2bf16(hi[3]);
  return o;
}

static __device__ __forceinline__ void gload_lds16(const void* g, void* l) {
  __builtin_amdgcn_global_load_lds(
      (const __attribute__((address_space(1))) void*)g,
      (__attribute__((address_space(3))) void*)l, 16, 0, 0);
}

// Pre-pass: W [8][512][512] fp32 -> Wp fragment-major bf16 (~3-4 us).
__global__ __launch_bounds__(256) void wprep_kernel(const float* __restrict__ W,
                                                    short* __restrict__ Wp) {
  const int gid  = blockIdx.x * 256 + threadIdx.x;
  const int lane = gid & 63;
  const int t    = (gid >> 6) & 15;
  const int cb   = (gid >> 10) & 31;
  const int nb   = gid >> 15;
  const int col  = cb * 16 + (lane & 15);
  const int k    = t * 32 + (lane >> 4) * 8;
  const float* src = W + (size_t)(nb * DOUT + col) * DIN + k;
  f32x4 lo = *(const f32x4*)src;
  f32x4 hi = *(const f32x4*)(src + 4);
  *(short8*)(Wp + (size_t)gid * 8) = cvt8(lo, hi);
}

// R15: controlled TLP test — R7's EXACT geometry/traffic/schedule (256x256
// tile, 48 KB staged/step, 16 barriers, counted vmcnt, 144 KB LDS, 1 blk/CU)
// but 16 waves of 64x64 (acc=64, ~90 VGPR, 4 waves/SIMD) instead of
// 8 waves of 64x128. Only per-wave ILP vs TLP changes.
// Per wave per stage: 2 A-DMA + 1 B-DMA -> steady vmcnt(3).
template <bool WPREP>
__global__ __launch_bounds__(1024, 1) void blocklinear_kernel(
    const float* __restrict__ x, const float* __restrict__ W,
    const short* __restrict__ Wp, const float* __restrict__ bias,
    float* __restrict__ y)
{
  // XCD swizzle (bijective: 512 % 8 == 0): one nb per XCD, nt innermost.
  const int b       = blockIdx.x;
  const int logical = (b & 7) * 64 + (b >> 3);
  const int nb  = logical >> 6;
  const int rem = logical & 63;
  const int mt  = rem >> 1;    // 0..31
  const int nt  = rem & 1;     // 0..1

  const int tid  = threadIdx.x;
  const int lane = tid & 63;
  const int w    = tid >> 6;   // wave 0..15
  const int wr   = w >> 2;     // M-row 0..3 (rows wr*64..+64)
  const int wn   = w & 3;      // N-col 0..3 (cols wn*64..+64)
  const int l15  = lane & 15;
  const int k16  = lane >> 4;

  __shared__ __align__(16) float Abuf[3][BM * 32];   // 3 x 32 KB
  __shared__ __align__(16) short Bbuf[3][BN * 32];   // 3 x 16 KB  (144 KB)

  // --- A staging: 32 x 1KB DMAs (256 rows x 128 B); wave w does 2 (i=0,1),
  // rows w*16 + i*8 + (l>>3). Dest chunk l&7 (linear); source chunk
  // pre-XOR'd (l&7)^(l>>3): stored slot s of row r = data chunk s^(r&7).
  const int l8 = lane >> 3;
  const int c  = lane & 7;
  const float* asrc[2];
#pragma unroll
  for (int i = 0; i < 2; ++i) {
    const int gr = mt * BM + w * 16 + i * 8 + l8;
    asrc[i] = x + (size_t)gr * NFEAT + nb * DIN + ((c ^ l8) << 2);
  }
  // --- B staging: 16 x 1KB chunks (one per 16-col frag); wave w does 1.
  const short* bsrc = WPREP
      ? Wp + ((size_t)(nb * 32 + nt * 16 + w) * 16) * 512 + lane * 8
      : nullptr;

#define STAGE(buf, t)                                                       \
  {                                                                         \
    _Pragma("unroll")                                                       \
    for (int i = 0; i < 2; ++i)                                             \
      gload_lds16(asrc[i] + (t) * 32, &Abuf[buf][(w * 16 + i * 8) * 32]);   \
    if constexpr (WPREP)                                                    \
      gload_lds16(bsrc + (t) * 512, &Bbuf[buf][w * 512]);                   \
  }

  // --- A fragment read offsets (floats): row = wr*64 + m*16 + l15
  // (row&7 == l15&7); addr = row*32 + slot*4, slot = (2k16 / 2k16+1)^(l15&7).
  const int ra_base = (wr * 64 + l15) * 32;
  const int ra_lo   = ra_base + (((2 * k16)     ^ (l15 & 7)) << 2);
  const int ra_hi   = ra_base + (((2 * k16 + 1) ^ (l15 & 7)) << 2);

  f32x4 acc[4][4];
#pragma unroll
  for (int m = 0; m < 4; ++m)
#pragma unroll
    for (int n = 0; n < 4; ++n)
      acc[m][n] = (f32x4){0.f, 0.f, 0.f, 0.f};

#define COMPUTE(buf)                                                        \
  {                                                                         \
    const float* la = &Abuf[buf][0];                                        \
    const short* lb = &Bbuf[buf][0];                                        \
    short8 af[4], bf[4];                                                    \
    _Pragma("unroll")                                                       \
    for (int m = 0; m < 4; ++m) {                                           \
      f32x4 lo = *(const f32x4*)(la + m * 512 + ra_lo);                     \
      f32x4 hi = *(const f32x4*)(la + m * 512 + ra_hi);                     \
      af[m] = cvt8(lo, hi);                                                 \
    }                                                                       \
    if constexpr (WPREP) {                                                  \
      _Pragma("unroll")                                                     \
      for (int n = 0; n < 4; ++n)                                           \
        bf[n] = *(const short8*)(lb + (wn * 4 + n) * 512 + lane * 8);       \
    } else {                                                                \
      _Pragma("unroll")                                                     \
      for (int n = 0; n < 4; ++n) {                                         \
        const int col = nt * BN + wn * 64 + n * 16 + l15;                   \
        const float* bp = W + (size_t)nb * DOUT * DIN + (size_t)col * DIN + \
                          CUR_T * 32 + k16 * 8;                             \
        bf[n] = cvt8(*(const f32x4*)bp, *(const f32x4*)(bp + 4));           \
      }                                                                     \
    }                                                                       \
    __builtin_amdgcn_s_setprio(1);                                          \
    _Pragma("unroll")                                                       \
    for (int m = 0; m < 4; ++m)                                             \
      _Pragma("unroll")                                                     \
      for (int n = 0; n < 4; ++n)                                           \
        acc[m][n] = __builtin_amdgcn_mfma_f32_16x16x32_bf16(af[m], bf[n], acc[m][n], 0, 0, 0); \
    __builtin_amdgcn_s_setprio(0);                                          \
  }

  // Step t: wait stage(t) landed (stage(t+1)'s 3/wave stay in flight ->
  // vmcnt(3)); barrier; stage(t+2) into the buffer all waves finished
  // reading at t-1; compute(t).
#define STEP(t, VMC)                                                        \
  {                                                                         \
    const int CUR_T = (t);                                                  \
    (void)CUR_T;                                                            \
    __builtin_amdgcn_sched_barrier(0);                                      \
    asm volatile("s_waitcnt vmcnt(" #VMC ")" ::: "memory");                 \
    __builtin_amdgcn_s_barrier();                                           \
    __builtin_amdgcn_sched_barrier(0);                                      \
    if ((t) + 2 < NT) STAGE(((t) + 2) % 3, (t) + 2);                        \
    COMPUTE((t) % 3);                                                       \
  }

  STAGE(0, 0);
  STAGE(1, 1);

  if constexpr (WPREP) {
    STEP(0, 3)  STEP(1, 3)  STEP(2, 3)  STEP(3, 3)
    STEP(4, 3)  STEP(5, 3)  STEP(6, 3)  STEP(7, 3)
    STEP(8, 3)  STEP(9, 3)  STEP(10, 3) STEP(11, 3)
    STEP(12, 3) STEP(13, 3) STEP(14, 3) STEP(15, 0)
  } else {
    STEP(0, 0)  STEP(1, 0)  STEP(2, 0)  STEP(3, 0)
    STEP(4, 0)  STEP(5, 0)  STEP(6, 0)  STEP(7, 0)
    STEP(8, 0)  STEP(9, 0)  STEP(10, 0) STEP(11, 0)
    STEP(12, 0) STEP(13, 0) STEP(14, 0) STEP(15, 0)
  }

  // epilogue: C/D layout col = lane&15, row = (lane>>4)*4 + j  [m89-verified]
  const int col0 = nt * BN + wn * 64;
  const int row0 = mt * BM + wr * 64;
  const float* bptr = bias + nb * DOUT + col0;
#pragma unroll
  for (int n = 0; n < 4; ++n) {
    const float bv = bptr[n * 16 + l15];
    const size_t col = (size_t)nb * DOUT + col0 + n * 16 + l15;
#pragma unroll
    for (int m = 0; m < 4; ++m) {
      const int row = row0 + m * 16 + k16 * 4;
      float* yp = y + (size_t)row * NFEAT + col;
#pragma unroll
      for (int j = 0; j < 4; ++j)
        yp[(size_t)j * NFEAT] = acc[m][n][j] + bv;
    }
  }
}

extern "C" void kernel_launch(void* const* d_in, const int* in_sizes, int n_in,
                              void* d_out, int out_size, void* d_ws, size_t ws_size,
                              hipStream_t stream) {
  const float* x  = (const float*)d_in[0];
  const float* W  = (const float*)d_in[1];
  const float* bi = (const float*)d_in[2];
  float* y = (float*)d_out;
  const size_t wp_bytes = (size_t)NBLK * DOUT * DIN * sizeof(short);  // 4 MiB
  const int grid = NBLK * (BATCH / BM) * (DOUT / BN);                 // 512

  if (ws_size >= wp_bytes) {
    short* Wp = (short*)d_ws;
    wprep_kernel<<<(NBLK * DOUT * DIN / 8) / 256, 256, 0, stream>>>(W, Wp);
    blocklinear_kernel<true><<<grid, 1024, 0, stream>>>(x, W, Wp, bi, y);
  } else {
    blocklinear_kernel<false><<<grid, 1024, 0, stream>>>(x, W, nullptr, bi, y);
  }
}